// Round 10
// baseline (269.396 us; speedup 1.0000x reference)
//
#include <hip/hip_runtime.h>

// ---------------- problem constants ----------------
#define B_      8
#define A_      64
#define NPAIR   63
#define NC_     128
#define NF_     2560    // K
#define O2_     196     // 14*14
#define NORB_   14
#define AO_     896
#define NCOLS   588     // valid cols: [H_off 196 | S_off 196 | H_on 196]
#define CSTRIDE 640     // padded col stride of HSoff
#define KSTEPS  80      // NF_/32
#define BM      128
#define BN      640
#define BSTEP_BYTES 40960   // BN*32*2 per K-step

typedef short bf16x8 __attribute__((ext_vector_type(8)));
typedef float f32x4  __attribute__((ext_vector_type(4)));

__device__ __forceinline__ unsigned f2bf(float f) {
    unsigned u = __builtin_bit_cast(unsigned, f);
    return (u + 0x7fffu + ((u >> 16) & 1u)) >> 16;   // RNE
}

// ---------------- kernel 1: fused {pack weights | energy head} ----------------
__global__ __launch_bounds__(512)
void prep_energy(const float* __restrict__ W_off, const float* __restrict__ W_ovoff,
                 const float* __restrict__ W_on, unsigned short* __restrict__ Bws,
                 const float* __restrict__ x, const float* __restrict__ W1,
                 const float* __restrict__ b1, const float* __restrict__ W2,
                 const float* __restrict__ b2, float* __restrict__ E) {
    const int t = threadIdx.x;
    if (blockIdx.x < KSTEPS) {
        __shared__ float wt[32 * BN];
        const int ks = blockIdx.x;
        for (int e = t; e < 32 * BN; e += 512) {
            int kl = e / BN, c = e - kl * BN;
            int kg = ks * 32 + kl;
            float v = 0.f;
            if (c < O2_)          v = W_off  [(size_t)kg * O2_ + c];
            else if (c < 2 * O2_) v = W_ovoff[(size_t)kg * O2_ + (c - O2_)];
            else if (c < 3 * O2_) v = W_on   [(size_t)kg * O2_ + (c - 2 * O2_)];
            wt[kl * BN + c] = v;
        }
        __syncthreads();
        unsigned short* out = Bws + (size_t)ks * (BN * 32);
        for (int e = t; e < BN * 4; e += 512) {
            int n = e >> 2, sg = e & 3;
            uint4 w;
            w.x = f2bf(wt[(sg * 8 + 0) * BN + n]) | (f2bf(wt[(sg * 8 + 1) * BN + n]) << 16);
            w.y = f2bf(wt[(sg * 8 + 2) * BN + n]) | (f2bf(wt[(sg * 8 + 3) * BN + n]) << 16);
            w.z = f2bf(wt[(sg * 8 + 4) * BN + n]) | (f2bf(wt[(sg * 8 + 5) * BN + n]) << 16);
            w.w = f2bf(wt[(sg * 8 + 6) * BN + n]) | (f2bf(wt[(sg * 8 + 7) * BN + n]) << 16);
            *(uint4*)(out + (size_t)n * 32 + sg * 8) = w;
        }
    } else {
        __shared__ float partial[8];
        const int b = blockIdx.x - KSTEPS;
        const int lane = t & 63;
        const int w = t >> 6;
        float esum = 0.f;
        for (int aa = 0; aa < 8; ++aa) {
            const int a = w * 8 + aa;
            const float* xr = x + (size_t)(b * A_ + a) * NC_;
            float hj = b1[lane];
            for (int k = 0; k < NC_; ++k) hj = fmaf(xr[k], W1[k * 64 + lane], hj);
            float sp = fmaxf(hj, 0.f) + log1pf(expf(-fabsf(hj))) - 0.69314718055994531f;
            float v = sp * W2[lane];
            for (int off = 32; off; off >>= 1) v += __shfl_down(v, off);
            if (lane == 0) esum += v + b2[0];
        }
        if (lane == 0) partial[w] = esum;
        __syncthreads();
        if (t == 0) {
            float e = 0.f;
            for (int k = 0; k < 8; ++k) e += partial[k];
            E[b] = e;
        }
    }
}

// ---------------- kernel 2: MFMA GEMM; BM=128, 16 waves, single barrier/step, conv pipelined into MFMA ----------------
// 16 waves 2Mx8N (wave 64x80, acc[4][5]); A: gload_lds fp32 (2-deep, issued at step top) ->
// conv pass (interleaved between MFMA clusters) -> bf16 slot-swizzled tile; B: global->reg 5-slot window.
__global__ __launch_bounds__(1024, 4)
void gemm_off(const float* __restrict__ V, const unsigned short* __restrict__ Bws,
              const float* __restrict__ b_off, const float* __restrict__ b_ovoff,
              const float* __restrict__ b_on, float* __restrict__ HSoff) {
    __shared__ alignas(16) float          Af32[2][BM * 32];        // 2 x 16 KB, linear
    __shared__ alignas(16) unsigned short Ab16[2][BM * 32];        // 2 x 8 KB, slot-swizzled

    const int tid  = threadIdx.x;
    const int mt   = blockIdx.x;
    const int lane = tid & 63;
    const int wv   = tid >> 6;                        // 0..15
    const int wm   = wv >> 3, wn = wv & 7;            // 2M x 8N, wave tile 64x80
    const int wvu  = __builtin_amdgcn_readfirstlane(wv);

    // linear fp32 stage: chunk tid (16B) = row tid>>3, float-seg tid&7 (coalesced 128B/row)
    const float* asrc = V + (size_t)(mt * BM + (tid >> 3)) * NF_ + (tid & 7) * 4;

    // B fragment base: frag(t, nf) at n = wn*80 + nf*16 + (lane&15), k-half (lane>>4)
    const char* bp = (const char*)Bws + (size_t)(wn * 80 + (lane & 15)) * 64 + (lane >> 4) * 16;
#define BFRAG(t_, nf_) (*(const bf16x8*)(bp + (size_t)(t_) * BSTEP_BYTES + (nf_) * 1024))

    f32x4 acc[4][5];
#pragma unroll
    for (int mf = 0; mf < 4; ++mf)
#pragma unroll
        for (int nf = 0; nf < 5; ++nf)
            acc[mf][nf] = (f32x4){0.f, 0.f, 0.f, 0.f};

    auto stage = [&](int buf, int t) {
        __builtin_amdgcn_global_load_lds(
            (const __attribute__((address_space(1))) void*)(asrc + (size_t)t * 32),
            (__attribute__((address_space(3))) void*)(&Af32[buf][wvu * 256]), 16, 0, 0);
    };

    // conv: thread's 16B fp32 -> 8B bf16 at swizzled slot (verified mapping, R9)
    const int crr = tid >> 3, cq = tid & 7;
    const int csl = ((cq >> 1) + ((crr + (crr >> 2)) & 3)) & 3;
    const unsigned cdst = (unsigned)(crr * 64 + csl * 16 + (cq & 1) * 8);

    const unsigned klo4 = (unsigned)(lane >> 4);

#define AFRAG(abf_, mf_, Bb16_) {                                                   \
    const unsigned R_ = (unsigned)(wm * 64 + (lane & 15) + (mf_) * 16);             \
    const unsigned sl_ = (klo4 + ((R_ + (R_ >> 2)) & 3)) & 3;                       \
    abf_ = *(const bf16x8*)((const char*)(Bb16_) + R_ * 64 + sl_ * 16); }

#define MFMA1(abf_, bq_, mf_, nf_) \
    acc[mf_][nf_] = __builtin_amdgcn_mfma_f32_16x16x32_bf16(abf_, bq_, acc[mf_][nf_], 0, 0, 0);

    bf16x8 bq0, bq1, bq2, bq3, bq4, af0, af1, af2, af3;

    // ---- prologue: stage chunks 0,1; B window(0); conv chunk 0 ----
    stage(0, 0);
    stage(1, 1);
    bq0 = BFRAG(0, 0); bq1 = BFRAG(0, 1); bq2 = BFRAG(0, 2); bq3 = BFRAG(0, 3); bq4 = BFRAG(0, 4);
    asm volatile("s_waitcnt vmcnt(6)" ::: "memory");     // retire stage(0); keep stage(1)+B in flight
    {
        float4 cf = *(const float4*)((const char*)&Af32[0][0] + tid * 16);
        unsigned lo, hi;
        asm("v_cvt_pk_bf16_f32 %0, %1, %2" : "=v"(lo) : "v"(cf.x), "v"(cf.y));
        asm("v_cvt_pk_bf16_f32 %0, %1, %2" : "=v"(hi) : "v"(cf.z), "v"(cf.w));
        uint2 cw = {lo, hi};
        *(uint2*)((char*)&Ab16[0][0] + cdst) = cw;
    }
    asm volatile("s_waitcnt lgkmcnt(0)" ::: "memory");
    __builtin_amdgcn_s_barrier();
    __builtin_amdgcn_sched_barrier(0);

    for (int t = 0; t < KSTEPS; ++t) {
        const int buf = t & 1;
        // stage(t+2) at step TOP: full-step latency cover; writes Af32[t&1]
        // (conv finished reading it in step t-1; barrier protects)
        if (t + 2 < KSTEPS) stage(buf, t + 2);

        // cluster 1: mf0, mf1. Implicit vmcnt waits on bq FIFO-retire stage(t+1) (older).
        AFRAG(af0, 0, &Ab16[buf][0]);
        AFRAG(af1, 1, &Ab16[buf][0]);
        __builtin_amdgcn_s_setprio(1);
        MFMA1(af0, bq0, 0, 0); MFMA1(af0, bq1, 0, 1); MFMA1(af0, bq2, 0, 2);
        MFMA1(af0, bq3, 0, 3); MFMA1(af0, bq4, 0, 4);
        MFMA1(af1, bq0, 1, 0); MFMA1(af1, bq1, 1, 1); MFMA1(af1, bq2, 1, 2);
        MFMA1(af1, bq3, 1, 3); MFMA1(af1, bq4, 1, 4);
        __builtin_amdgcn_s_setprio(0);

        // conv chunk t+1 (reads Af32[(t+1)&1], staged at top of step t-1; fenced by vmcnt asm)
        if (t + 1 < KSTEPS) {
            asm volatile("s_waitcnt vmcnt(5)" ::: "memory");   // no-op bound; fences ds_read below
            float4 cf = *(const float4*)((const char*)&Af32[buf ^ 1][0] + tid * 16);
            unsigned lo, hi;
            asm("v_cvt_pk_bf16_f32 %0, %1, %2" : "=v"(lo) : "v"(cf.x), "v"(cf.y));
            asm("v_cvt_pk_bf16_f32 %0, %1, %2" : "=v"(hi) : "v"(cf.z), "v"(cf.w));
            uint2 cw = {lo, hi};
            *(uint2*)((char*)&Ab16[buf ^ 1][0] + cdst) = cw;
        }

        // cluster 2: mf2, mf3; B-window reloads at last use
        AFRAG(af2, 2, &Ab16[buf][0]);
        AFRAG(af3, 3, &Ab16[buf][0]);
        __builtin_amdgcn_s_setprio(1);
        MFMA1(af2, bq0, 2, 0); MFMA1(af3, bq0, 3, 0); bq0 = BFRAG(t + 1, 0);
        MFMA1(af2, bq1, 2, 1); MFMA1(af3, bq1, 3, 1); bq1 = BFRAG(t + 1, 1);
        MFMA1(af2, bq2, 2, 2); MFMA1(af3, bq2, 3, 2); bq2 = BFRAG(t + 1, 2);
        MFMA1(af2, bq3, 2, 3); MFMA1(af3, bq3, 3, 3); bq3 = BFRAG(t + 1, 3);
        MFMA1(af2, bq4, 2, 4); MFMA1(af3, bq4, 3, 4); bq4 = BFRAG(t + 1, 4);
        __builtin_amdgcn_s_setprio(0);

        asm volatile("s_waitcnt lgkmcnt(0)" ::: "memory");     // conv write + frag reads done
        __builtin_amdgcn_sched_barrier(0);
        __builtin_amdgcn_s_barrier();
        __builtin_amdgcn_sched_barrier(0);
    }

    // ---- epilogue: C/D layout col=lane&15, row=(lane>>4)*4+reg ----
    const int c16 = lane & 15, rg = lane >> 4;
#pragma unroll
    for (int nf = 0; nf < 5; ++nf) {
        int C = wn * 80 + nf * 16 + c16;
        if (C >= NCOLS) continue;
        float bias = (C < O2_) ? b_off[C] : (C < 2 * O2_) ? b_ovoff[C - O2_] : b_on[C - 2 * O2_];
#pragma unroll
        for (int mf = 0; mf < 4; ++mf) {
            int R = mt * BM + wm * 64 + mf * 16 + rg * 4;
            float* o = HSoff + (size_t)R * CSTRIDE + C;
            o[0]           = acc[mf][nf][0] + bias;
            o[CSTRIDE]     = acc[mf][nf][1] + bias;
            o[2 * CSTRIDE] = acc[mf][nf][2] + bias;
            o[3 * CSTRIDE] = acc[mf][nf][3] + bias;
        }
    }
#undef BFRAG
#undef AFRAG
#undef MFMA1
}

// ---------------- kernel 3: Hon = rowmean over 63 pair rows of cols [392,588) ----------------
__global__ void hon_reduce(const float* __restrict__ HSoff, float* __restrict__ Hon) {
    const int g = blockIdx.x;       // 0..511
    const int t = threadIdx.x;      // 256, t<196 active
    if (t >= O2_) return;
    const float* p0 = HSoff + (size_t)g * NPAIR * CSTRIDE + 2 * O2_ + t;
    const float* p1 = p0 + (size_t)21 * CSTRIDE;
    const float* p2 = p0 + (size_t)42 * CSTRIDE;
    float a0 = 0.f, a1 = 0.f, a2 = 0.f;
#pragma unroll 3
    for (int j = 0; j < 21; ++j) {
        a0 += p0[0]; a1 += p1[0]; a2 += p2[0];
        p0 += CSTRIDE; p1 += CSTRIDE; p2 += CSTRIDE;
    }
    Hon[(size_t)g * O2_ + t] = (a0 + a1 + a2) * (1.f / (float)NPAIR);
}

// ---------------- kernel 4: assemble H and S, LDS-staged, fully coalesced ----------------
__global__ __launch_bounds__(256)
void assemble_k(const float* __restrict__ HSoff, const float* __restrict__ Hon,
                const int* __restrict__ Z, const float* __restrict__ ov_emb,
                const float* __restrict__ orbE, const float* __restrict__ s0E,
                float* __restrict__ H, float* __restrict__ S) {
    __shared__ float Ai[NPAIR * 197];
    __shared__ float Bj[2][16 * 200];
    __shared__ float Dg[O2_];
    __shared__ float Dd[NORB_];

    const int bid = blockIdx.x;
    const int h = bid & 1, i = (bid >> 1) & 63, b = bid >> 7;
    const int t = threadIdx.x;
    const int g = b * A_ + i;
    const int z = Z[g];
    float* out = (h ? S : H) + (size_t)b * AO_ * AO_;

    const float* abase = HSoff + (size_t)g * NPAIR * CSTRIDE + h * O2_;
    for (int u = t; u < NPAIR * O2_; u += 256) {
        int jj = u / O2_, e = u - jj * O2_;
        Ai[jj * 197 + e] = abase[(size_t)jj * CSTRIDE + e];
    }
    if (t < O2_)   Dg[t] = h ? ov_emb[(size_t)z * O2_ + t]   : Hon[(size_t)g * O2_ + t];
    if (t < NORB_) Dd[t] = h ? s0E[(size_t)z * NORB_ + t]    : orbE[(size_t)z * NORB_ + t];

    auto stageB = [&](int buf, int jc) {
        for (int u = t; u < 16 * O2_; u += 256) {
            int jl = u / O2_, e = u - jl * O2_;
            int j = jc * 16 + jl;
            if (j != i) {
                int idx = (i < j) ? i : i - 1;
                Bj[buf][jl * 200 + e] =
                    HSoff[((size_t)(b * A_ + j) * NPAIR + idx) * CSTRIDE + h * O2_ + e];
            }
        }
    };
    stageB(0, 0);
    __syncthreads();

    const int tj = t / NORB_, tq = t - tj * NORB_;   // valid for t<224
    for (int jc = 0; jc < 4; ++jc) {
        if (jc < 3) stageB((jc + 1) & 1, jc + 1);
        if (t < 224) {
            const int j = jc * 16 + tj;
            const int cur = jc & 1;
#pragma unroll
            for (int p = 0; p < NORB_; ++p) {
                float v;
                if (j == i) {
                    v = 0.5f * (Dg[p * NORB_ + tq] + Dg[tq * NORB_ + p]);
                    if (p == tq) v += Dd[p];
                } else {
                    int jj = (j < i) ? j : j - 1;
                    v = 0.5f * (Ai[jj * 197 + p * NORB_ + tq] + Bj[cur][tj * 200 + tq * NORB_ + p]);
                }
                out[(size_t)(i * NORB_ + p) * AO_ + jc * 224 + t] = v;
            }
        }
        __syncthreads();
    }
}

// ---------------- launcher ----------------
extern "C" void kernel_launch(void* const* d_in, const int* in_sizes, int n_in,
                              void* d_out, int out_size, void* d_ws, size_t ws_size,
                              hipStream_t stream) {
    const int*   Z       = (const int*)  d_in[0];
    const float* x       = (const float*)d_in[2];
    const float* V       = (const float*)d_in[3];
    const float* W_off   = (const float*)d_in[4];
    const float* b_off   = (const float*)d_in[5];
    const float* W_on    = (const float*)d_in[6];
    const float* b_on    = (const float*)d_in[7];
    const float* W_ovoff = (const float*)d_in[8];
    const float* b_ovoff = (const float*)d_in[9];
    const float* ov_emb  = (const float*)d_in[10];
    const float* orbE    = (const float*)d_in[11];
    const float* s0E     = (const float*)d_in[12];
    const float* W1      = (const float*)d_in[13];
    const float* b1      = (const float*)d_in[14];
    const float* W2      = (const float*)d_in[15];
    const float* b2      = (const float*)d_in[16];

    float* H = (float*)d_out;
    float* S = H + (size_t)B_ * AO_ * AO_;
    float* E = S + (size_t)B_ * AO_ * AO_;

    char* ws = (char*)d_ws;
    unsigned short* Bws = (unsigned short*)ws;                     // 81 steps x 40960 B (step 80 = pad)
    float* HSoff = (float*)(ws + (size_t)4  * 1024 * 1024);        // 82,575,360 B
    float* Hon   = (float*)(ws + (size_t)88 * 1024 * 1024);        //    401,408 B

    prep_energy<<<KSTEPS + B_, 512, 0, stream>>>(W_off, W_ovoff, W_on, Bws,
                                                 x, W1, b1, W2, b2, E);
    gemm_off   <<<252,  1024, 0, stream>>>(V, Bws, b_off, b_ovoff, b_on, HSoff);
    hon_reduce <<<512,  256,  0, stream>>>(HSoff, Hon);
    assemble_k <<<1024, 256,  0, stream>>>(HSoff, Hon, Z, ov_emb, orbE, s0E, H, S);
}

// Round 12
// 252.579 us; speedup vs baseline: 1.0666x; 1.0666x over previous
//
#include <hip/hip_runtime.h>

// ---------------- problem constants ----------------
#define B_      8
#define A_      64
#define NPAIR   63
#define NC_     128
#define NF_     2560    // K
#define O2_     196     // 14*14
#define NORB_   14
#define AO_     896
#define NCOLS   588     // computed cols: [H_off 196 | S_off 196 | H_on 196]
#define NSTORE  392     // cols stored to HSoff
#define CSTRIDE 400     // padded col stride of HSoff (1600 B)
#define KSTEPS  80      // NF_/32
#define BM      126     // 2 atoms x 63 pair-rows per block
#define BN      640
#define BSTEP_BYTES 40960   // BN*32*2 per K-step

typedef short bf16x8 __attribute__((ext_vector_type(8)));
typedef float f32x4  __attribute__((ext_vector_type(4)));

__device__ __forceinline__ unsigned f2bf(float f) {
    unsigned u = __builtin_bit_cast(unsigned, f);
    return (u + 0x7fffu + ((u >> 16) & 1u)) >> 16;   // RNE
}

// ---------------- kernel 1: fused {pack weights | energy head} ----------------
__global__ __launch_bounds__(512)
void prep_energy(const float* __restrict__ W_off, const float* __restrict__ W_ovoff,
                 const float* __restrict__ W_on, unsigned short* __restrict__ Bws,
                 const float* __restrict__ x, const float* __restrict__ W1,
                 const float* __restrict__ b1, const float* __restrict__ W2,
                 const float* __restrict__ b2, float* __restrict__ E) {
    const int t = threadIdx.x;
    if (blockIdx.x < KSTEPS) {
        __shared__ float wt[32 * BN];
        const int ks = blockIdx.x;
        for (int e = t; e < 32 * BN; e += 512) {
            int kl = e / BN, c = e - kl * BN;
            int kg = ks * 32 + kl;
            float v = 0.f;
            if (c < O2_)          v = W_off  [(size_t)kg * O2_ + c];
            else if (c < 2 * O2_) v = W_ovoff[(size_t)kg * O2_ + (c - O2_)];
            else if (c < 3 * O2_) v = W_on   [(size_t)kg * O2_ + (c - 2 * O2_)];
            wt[kl * BN + c] = v;
        }
        __syncthreads();
        unsigned short* out = Bws + (size_t)ks * (BN * 32);
        for (int e = t; e < BN * 4; e += 512) {
            int n = e >> 2, sg = e & 3;
            uint4 w;
            w.x = f2bf(wt[(sg * 8 + 0) * BN + n]) | (f2bf(wt[(sg * 8 + 1) * BN + n]) << 16);
            w.y = f2bf(wt[(sg * 8 + 2) * BN + n]) | (f2bf(wt[(sg * 8 + 3) * BN + n]) << 16);
            w.z = f2bf(wt[(sg * 8 + 4) * BN + n]) | (f2bf(wt[(sg * 8 + 5) * BN + n]) << 16);
            w.w = f2bf(wt[(sg * 8 + 6) * BN + n]) | (f2bf(wt[(sg * 8 + 7) * BN + n]) << 16);
            *(uint4*)(out + (size_t)n * 32 + sg * 8) = w;
        }
    } else {
        __shared__ float partial[8];
        const int b = blockIdx.x - KSTEPS;
        const int lane = t & 63;
        const int w = t >> 6;
        float esum = 0.f;
        for (int aa = 0; aa < 8; ++aa) {
            const int a = w * 8 + aa;
            const float* xr = x + (size_t)(b * A_ + a) * NC_;
            float hj = b1[lane];
            for (int k = 0; k < NC_; ++k) hj = fmaf(xr[k], W1[k * 64 + lane], hj);
            float sp = fmaxf(hj, 0.f) + log1pf(expf(-fabsf(hj))) - 0.69314718055994531f;
            float v = sp * W2[lane];
            for (int off = 32; off; off >>= 1) v += __shfl_down(v, off);
            if (lane == 0) esum += v + b2[0];
        }
        if (lane == 0) partial[w] = esum;
        __syncthreads();
        if (t == 0) {
            float e = 0.f;
            for (int k = 0; k < 8; ++k) e += partial[k];
            E[b] = e;
        }
    }
}

// ---------------- kernel 2: MFMA GEMM + fused Hon reduction ----------------
// BM=126 (atoms 2mt,2mt+1), 256 blocks (1/CU), 16 waves 2Mx8N, acc[4][5].
// Issue order per step: conv(vmcnt6) -> MFMA/bq -> bq(t+1) reloads -> stage s(t+4) LAST
// so B-window waits never retire-chain on the A-DMA (FIFO vmcnt decoupling).
__global__ __launch_bounds__(1024, 4)
void gemm_off(const float* __restrict__ V, const unsigned short* __restrict__ Bws,
              const float* __restrict__ b_off, const float* __restrict__ b_ovoff,
              const float* __restrict__ b_on, float* __restrict__ HSoff,
              float* __restrict__ Hon) {
    __shared__ alignas(16) float          Af32[4][4096];   // 4 x 16 KB slots (126 rows x 128 B used)
    __shared__ alignas(16) unsigned short Ab16[3][4096];   // 3 x 8 KB slots (126 rows x 64 B used)
    __shared__ float HonLds[2][O2_];

    const int tid  = threadIdx.x;
    const int mt   = blockIdx.x;
    const int lane = tid & 63;
    const int wv   = tid >> 6;                 // 0..15
    const int wm   = wv >> 3, wn = wv & 7;     // 2M x 8N, wave tile 64x80
    const int wvu  = __builtin_amdgcn_readfirstlane(wv);
    const bool sthr = tid < BM * 8;            // 1008 staging/conv threads

    // staging: thread -> (row rr=tid>>3, k-seg tid&7), 16 B chunks, coalesced 128 B/row
    const float* asrc = V + (size_t)(mt * BM + (tid >> 3)) * NF_ + (tid & 7) * 4;

    // B fragment base: frag(t,nf) at n = wn*80 + nf*16 + (lane&15), k-quarter (lane>>4)
    const char* bp = (const char*)Bws + (size_t)(wn * 80 + (lane & 15)) * 64 + (lane >> 4) * 16;
#define BFRAG(t_, nf_) (*(const bf16x8*)(bp + (size_t)(t_) * BSTEP_BYTES + (nf_) * 1024))

    f32x4 acc[4][5];
#pragma unroll
    for (int mf = 0; mf < 4; ++mf)
#pragma unroll
        for (int nf = 0; nf < 5; ++nf)
            acc[mf][nf] = (f32x4){0.f, 0.f, 0.f, 0.f};

    auto stage = [&](int slot, int kk) {       // kk = K-step index (pre-clamped)
        if (sthr)
            __builtin_amdgcn_global_load_lds(
                (const __attribute__((address_space(1))) void*)(asrc + (size_t)kk * 32),
                (__attribute__((address_space(3))) void*)(&Af32[slot][wvu * 256]), 16, 0, 0);
    };

    // conv: thread's 16B fp32 -> 8B bf16 at slot-swizzled position (mapping verified R9)
    const int crr = tid >> 3, cq = tid & 7;
    const int csl = ((cq >> 1) + ((crr + (crr >> 2)) & 3)) & 3;
    const unsigned cdst = (unsigned)(crr * 64 + csl * 16 + (cq & 1) * 8);
    auto conv = [&](int fslot, int bslot) {
        if (sthr) {
            float4 cf = *(const float4*)((const char*)&Af32[fslot][0] + tid * 16);
            unsigned lo, hi;
            asm("v_cvt_pk_bf16_f32 %0, %1, %2" : "=v"(lo) : "v"(cf.x), "v"(cf.y));
            asm("v_cvt_pk_bf16_f32 %0, %1, %2" : "=v"(hi) : "v"(cf.z), "v"(cf.w));
            uint2 cw = {lo, hi};
            *(uint2*)((char*)&Ab16[bslot][0] + cdst) = cw;
        }
    };

    const unsigned klo4 = (unsigned)(lane >> 4);
#define AFRAG(abf_, mf_, Bb16_) {                                                   \
    const unsigned R_ = (unsigned)(wm * 64 + (lane & 15) + (mf_) * 16);             \
    const unsigned sl_ = (klo4 + ((R_ + (R_ >> 2)) & 3)) & 3;                       \
    abf_ = *(const bf16x8*)((const char*)(Bb16_) + R_ * 64 + sl_ * 16); }

#define MFMA1(abf_, bq_, mf_, nf_) \
    acc[mf_][nf_] = __builtin_amdgcn_mfma_f32_16x16x32_bf16(abf_, bq_, acc[mf_][nf_], 0, 0, 0);

    bf16x8 bq0, bq1, bq2, bq3, bq4, abf;

    // ---- prologue: s0..s3, bq(0); conv A0, A1 ----
    stage(0, 0); stage(1, 1); stage(2, 2); stage(3, 3);
    bq0 = BFRAG(0, 0); bq1 = BFRAG(0, 1); bq2 = BFRAG(0, 2); bq3 = BFRAG(0, 3); bq4 = BFRAG(0, 4);
    asm volatile("s_waitcnt vmcnt(8)" ::: "memory");   // retire s0
    __builtin_amdgcn_sched_barrier(0);
    conv(0, 0);
    asm volatile("s_waitcnt vmcnt(7)" ::: "memory");   // retire s1
    __builtin_amdgcn_sched_barrier(0);
    conv(1, 1);
    asm volatile("s_waitcnt lgkmcnt(0)" ::: "memory");
    __builtin_amdgcn_s_barrier();
    __builtin_amdgcn_sched_barrier(0);

    for (int t = 0; t < KSTEPS; ++t) {
        // conv A(t+2): only wait = s(t+2); leaves bq(t) x5 + s(t+3) in flight
        if (t + 2 < KSTEPS) {
            asm volatile("s_waitcnt vmcnt(6)" ::: "memory");
            __builtin_amdgcn_sched_barrier(0);
            conv((t + 2) & 3, (t + 2) % 3);
        }

        // MFMA phase on Ab16[t%3] with bq(t); bq(t+1) reloads at last use (mf==3)
        const unsigned short* At = &Ab16[t % 3][0];
#pragma unroll
        for (int mf = 0; mf < 4; ++mf) {
            AFRAG(abf, mf, At);
            __builtin_amdgcn_s_setprio(1);
            MFMA1(abf, bq0, mf, 0); if (mf == 3) bq0 = BFRAG(t + 1, 0);  // t=79 -> pad step 80
            MFMA1(abf, bq1, mf, 1); if (mf == 3) bq1 = BFRAG(t + 1, 1);
            MFMA1(abf, bq2, mf, 2); if (mf == 3) bq2 = BFRAG(t + 1, 2);
            MFMA1(abf, bq3, mf, 3); if (mf == 3) bq3 = BFRAG(t + 1, 3);
            MFMA1(abf, bq4, mf, 4); if (mf == 3) bq4 = BFRAG(t + 1, 4);
            __builtin_amdgcn_s_setprio(0);
        }

        // stage s(t+4) LAST (newest in FIFO; clamped dummy keeps counts uniform in tail)
        {
            int kk = t + 4 < KSTEPS ? t + 4 : KSTEPS - 1;
            stage((t + 4) & 3, kk);
        }
        asm volatile("s_waitcnt lgkmcnt(0)" ::: "memory");
        __builtin_amdgcn_sched_barrier(0);
        __builtin_amdgcn_s_barrier();
        __builtin_amdgcn_sched_barrier(0);
    }

    // ---- epilogue ----
    asm volatile("s_waitcnt vmcnt(0)" ::: "memory");   // drain dummy stages before LDS reuse
    if (tid < 2 * O2_) HonLds[tid / O2_][tid % O2_] = 0.f;
    __syncthreads();

    const int c16 = lane & 15, rg = lane >> 4;
    // off-site cols -> HSoff (+bias)
#pragma unroll
    for (int nf = 0; nf < 5; ++nf) {
        const int C = wn * 80 + nf * 16 + c16;
        if (C >= NSTORE) continue;
        const float bias = (C < O2_) ? b_off[C] : b_ovoff[C - O2_];
#pragma unroll
        for (int mf = 0; mf < 4; ++mf) {
            const int L = wm * 64 + mf * 16 + rg * 4;
#pragma unroll
            for (int jj = 0; jj < 4; ++jj) {
                const int row = L + jj;
                if (row < BM)
                    HSoff[(size_t)(mt * BM + row) * CSTRIDE + C] = acc[mf][nf][jj] + bias;
            }
        }
    }
    // on-site cols -> in-block mean reduction
#pragma unroll
    for (int nf = 0; nf < 5; ++nf) {
        const int C = wn * 80 + nf * 16 + c16;
        if (C < NSTORE || C >= NCOLS) continue;
        const int cc = C - NSTORE;
        float s0 = 0.f, s1 = 0.f;
#pragma unroll
        for (int mf = 0; mf < 4; ++mf) {
            const int L = wm * 64 + mf * 16 + rg * 4;
#pragma unroll
            for (int jj = 0; jj < 4; ++jj) {
                const int row = L + jj;
                const float v = acc[mf][nf][jj];
                if (row < NPAIR)            s0 += v;
                else if (row < BM)          s1 += v;
            }
        }
        s0 += __shfl_down(s0, 32); s0 += __shfl_down(s0, 16);
        s1 += __shfl_down(s1, 32); s1 += __shfl_down(s1, 16);
        if (lane < 16) {
            atomicAdd(&HonLds[0][cc], s0);
            atomicAdd(&HonLds[1][cc], s1);
        }
    }
    __syncthreads();
    if (tid < 2 * O2_) {
        const int atom = tid / O2_, c = tid % O2_;
        Hon[(size_t)(mt * 2 + atom) * O2_ + c] =
            HonLds[atom][c] * (1.f / (float)NPAIR) + b_on[c];
    }
#undef BFRAG
#undef AFRAG
#undef MFMA1
}

// ---------------- kernel 3: assemble H and S, LDS-staged, fully coalesced ----------------
__global__ __launch_bounds__(256)
void assemble_k(const float* __restrict__ HSoff, const float* __restrict__ Hon,
                const int* __restrict__ Z, const float* __restrict__ ov_emb,
                const float* __restrict__ orbE, const float* __restrict__ s0E,
                float* __restrict__ H, float* __restrict__ S) {
    __shared__ float Ai[NPAIR * 197];
    __shared__ float Bj[2][16 * 200];
    __shared__ float Dg[O2_];
    __shared__ float Dd[NORB_];

    const int bid = blockIdx.x;
    const int h = bid & 1, i = (bid >> 1) & 63, b = bid >> 7;
    const int t = threadIdx.x;
    const int g = b * A_ + i;
    const int z = Z[g];
    float* out = (h ? S : H) + (size_t)b * AO_ * AO_;

    const float* abase = HSoff + (size_t)g * NPAIR * CSTRIDE + h * O2_;
    for (int u = t; u < NPAIR * O2_; u += 256) {
        int jj = u / O2_, e = u - jj * O2_;
        Ai[jj * 197 + e] = abase[(size_t)jj * CSTRIDE + e];
    }
    if (t < O2_)   Dg[t] = h ? ov_emb[(size_t)z * O2_ + t]   : Hon[(size_t)g * O2_ + t];
    if (t < NORB_) Dd[t] = h ? s0E[(size_t)z * NORB_ + t]    : orbE[(size_t)z * NORB_ + t];

    auto stageB = [&](int buf, int jc) {
        for (int u = t; u < 16 * O2_; u += 256) {
            int jl = u / O2_, e = u - jl * O2_;
            int j = jc * 16 + jl;
            if (j != i) {
                int idx = (i < j) ? i : i - 1;
                Bj[buf][jl * 200 + e] =
                    HSoff[((size_t)(b * A_ + j) * NPAIR + idx) * CSTRIDE + h * O2_ + e];
            }
        }
    };
    stageB(0, 0);
    __syncthreads();

    const int tj = t / NORB_, tq = t - tj * NORB_;   // valid for t<224
    for (int jc = 0; jc < 4; ++jc) {
        if (jc < 3) stageB((jc + 1) & 1, jc + 1);
        if (t < 224) {
            const int j = jc * 16 + tj;
            const int cur = jc & 1;
#pragma unroll
            for (int p = 0; p < NORB_; ++p) {
                float v;
                if (j == i) {
                    v = 0.5f * (Dg[p * NORB_ + tq] + Dg[tq * NORB_ + p]);
                    if (p == tq) v += Dd[p];
                } else {
                    int jj = (j < i) ? j : j - 1;
                    v = 0.5f * (Ai[jj * 197 + p * NORB_ + tq] + Bj[cur][tj * 200 + tq * NORB_ + p]);
                }
                out[(size_t)(i * NORB_ + p) * AO_ + jc * 224 + t] = v;
            }
        }
        __syncthreads();
    }
}

// ---------------- launcher ----------------
extern "C" void kernel_launch(void* const* d_in, const int* in_sizes, int n_in,
                              void* d_out, int out_size, void* d_ws, size_t ws_size,
                              hipStream_t stream) {
    const int*   Z       = (const int*)  d_in[0];
    const float* x       = (const float*)d_in[2];
    const float* V       = (const float*)d_in[3];
    const float* W_off   = (const float*)d_in[4];
    const float* b_off   = (const float*)d_in[5];
    const float* W_on    = (const float*)d_in[6];
    const float* b_on    = (const float*)d_in[7];
    const float* W_ovoff = (const float*)d_in[8];
    const float* b_ovoff = (const float*)d_in[9];
    const float* ov_emb  = (const float*)d_in[10];
    const float* orbE    = (const float*)d_in[11];
    const float* s0E     = (const float*)d_in[12];
    const float* W1      = (const float*)d_in[13];
    const float* b1      = (const float*)d_in[14];
    const float* W2      = (const float*)d_in[15];
    const float* b2      = (const float*)d_in[16];

    float* H = (float*)d_out;
    float* S = H + (size_t)B_ * AO_ * AO_;
    float* E = S + (size_t)B_ * AO_ * AO_;

    char* ws = (char*)d_ws;
    unsigned short* Bws = (unsigned short*)ws;                     // 81 steps x 40960 B (step 80 = pad)
    float* HSoff = (float*)(ws + (size_t)4  * 1024 * 1024);        // 32256*400*4 = 51,609,600 B
    float* Hon   = (float*)(ws + (size_t)60 * 1024 * 1024);        //    401,408 B

    prep_energy<<<KSTEPS + B_, 512, 0, stream>>>(W_off, W_ovoff, W_on, Bws,
                                                 x, W1, b1, W2, b2, E);
    gemm_off   <<<256,  1024, 0, stream>>>(V, Bws, b_off, b_ovoff, b_on, HSoff, Hon);
    assemble_k <<<1024, 256,  0, stream>>>(HSoff, Hon, Z, ov_emb, orbE, s0E, H, S);
}